// Round 13
// baseline (1005.877 us; speedup 1.0000x reference)
//
#include <hip/hip_runtime.h>
#include <hip/hip_bf16.h>
#include <stdint.h>

typedef __hip_bfloat16 bf16_t;
typedef __attribute__((ext_vector_type(8))) short short8;
typedef __attribute__((ext_vector_type(4))) float f32x4;
typedef __attribute__((ext_vector_type(4))) unsigned int u32x4;
typedef unsigned long long ull;

#define MFMA16(a, b, c) __builtin_amdgcn_mfma_f32_16x16x32_bf16(a, b, c, 0, 0, 0)

#define NROW 50176   // B*S*S
#define NBATCH 1792  // B*S

__device__ __forceinline__ void g2l16(const void* g, void* l) {
  __builtin_amdgcn_global_load_lds(
      (const __attribute__((address_space(1))) unsigned int*)g,
      (__attribute__((address_space(3))) unsigned int*)l, 16, 0, 0);
}
__device__ __forceinline__ float sigm(float x) { return 1.0f / (1.0f + __expf(-x)); }
__device__ __forceinline__ float tanh_(float x) { return 2.0f / (1.0f + __expf(-2.0f * x)) - 1.0f; }
__device__ __forceinline__ void stc(bf16_t* p, float v) { *p = __float2bfloat16(v); }
__device__ __forceinline__ void stc(float* p, float v) { *p = v; }
__device__ __forceinline__ float bf2f(unsigned short u) {
  return __uint_as_float((unsigned int)u << 16);
}

// ---- fp32 -> bf16 conversion of all 8 LSTM weight matrices in one launch
struct CvtArgs {
  const float* src[8];
  bf16_t* dst[8];
  int n[8];
};
__global__ void cvt_all(CvtArgs a) {
  int arr = blockIdx.y;
  int i = blockIdx.x * 256 + threadIdx.x;
  if (i < a.n[arr]) a.dst[arr][i] = __float2bfloat16(a.src[arr][i]);
}

// ---- K0a: x fp32 [B,512,28,28] -> Xin K-grouped [16][50176][32] bf16
// FUSED: also emits x_s[b][c][k] = x[b][c][3kh][3kw] for rows h = 3kh (the tile
// already holds them), and zero-pads k in [100,128) once (h==0 blocks).
__global__ void transpose_x(const float* __restrict__ x, bf16_t* __restrict__ Xin,
                            bf16_t* __restrict__ xs) {
  int c0 = blockIdx.x * 128, h = blockIdx.y, b = blockIdx.z;
  __shared__ __align__(16) short tile[128 * 29];
  const float* xb = x + ((size_t)b * 512 + c0) * 784 + h * 28;
  for (int e = threadIdx.x; e < 128 * 28; e += 256) {
    int cc = e / 28, w = e - cc * 28;
    tile[cc * 29 + w] = __bfloat16_as_short(__float2bfloat16(xb[(size_t)cc * 784 + w]));
  }
  __syncthreads();
  size_t orow0 = (size_t)(b * 28 + h) * 28;
  short* os = (short*)Xin;
  for (int e = threadIdx.x; e < 28 * 128; e += 256) {
    int w = e >> 7, cc = e & 127;
    int c = c0 + cc;
    os[(size_t)(c >> 5) * NROW * 32 + (orow0 + w) * 32 + (c & 31)] = tile[cc * 29 + w];
  }
  short* xss = (short*)xs;
  if (h % 3 == 0) {  // h in {0,3,...,27} -> kh = h/3 in 0..9
    int kh = h / 3;
    for (int e = threadIdx.x; e < 1280; e += 256) {
      int cc = e / 10, kw = e - cc * 10;
      xss[((size_t)(b * 512) + c0 + cc) * 128 + kh * 10 + kw] = tile[cc * 29 + 3 * kw];
    }
  }
  if (h == 0) {  // zero pad cols 100..127
    for (int e = threadIdx.x; e < 128 * 28; e += 256) {
      int cc = e / 28, kp = e - cc * 28;
      xss[((size_t)(b * 512) + c0 + cc) * 128 + 100 + kp] = 0;
    }
  }
}

// ---- K0c: pad conv_w fp32 [100,512] -> bf16 [128,512]; conv_b fp32 [100] -> fp32 [128]
//      also zero the per-(group,wave) flag counters (2 scans x 3584 u32)
__global__ void pad_conv(const float* __restrict__ cw, const float* __restrict__ cb,
                         bf16_t* __restrict__ cwp, float* __restrict__ cbp,
                         unsigned int* __restrict__ bar) {
  int r = blockIdx.x;  // 128
  if (r == 0)
    for (int i = threadIdx.x; i < 7168; i += 128) bar[i] = 0;
  for (int i = threadIdx.x; i < 512; i += 128)
    cwp[r * 512 + i] = __float2bfloat16((r < 100) ? cw[r * 512 + i] : 0.0f);
  if (r == 0) cbp[threadIdx.x] = (threadIdx.x < 100) ? cb[threadIdx.x] : 0.0f;
}

// ---- K1 (best-measured structure): C[M,Nphys] = A[M,K] @ Bsel^T + bias.
// A is K-grouped [K/32][M][32] (8KB contiguous per 128x32 tile). CPERM: output
// cols permuted to dir*1024 + js*128 + gate*32 + jj (lstm-block-local 256B/row);
// B rows consumed in (gate,jj) order, bias index-remapped; C-store addresses
// contiguous. BK=64: two k-group panels per barrier pair -> 32 MFMA between
// barriers. Panel row stride 64B (free 2-way bank aliasing).
template <typename CT, bool CPERM>
__global__ __launch_bounds__(256) void gemm_bt(
    const bf16_t* __restrict__ A, const bf16_t* __restrict__ B0,
    const bf16_t* __restrict__ B1, const float* __restrict__ bias0,
    const float* __restrict__ bias1, CT* __restrict__ C, int M, int N, int K) {
  __shared__ __align__(16) short As[2][128 * 32];
  __shared__ __align__(16) short Bs[2][128 * 32];
  int tid = threadIdx.x;
  int nb = blockIdx.x;
  int bm0 = blockIdx.y * 128, bn0 = nb * 128;
  int lrow = tid >> 2, lseg = tid & 3;  // 4 threads x 16B cover one 32-elem row
  const char* Ag = (const char*)A + ((size_t)(bm0 + lrow) * 32 + lseg * 8) * 2;
  size_t Aadv = (size_t)M * 64;
  const float* biasp;
  const char *Bg1, *Bg2;
  int js = 0;
  if (CPERM) {
    int dir = nb >> 3;
    js = nb & 7;
    const bf16_t* Bsel = dir ? B1 : B0;
    biasp = dir ? bias1 : bias0;
    int br1 = (lrow >> 5) * 256 + js * 32 + (lrow & 31);          // gates 0,1
    int br2 = ((lrow + 64) >> 5) * 256 + js * 32 + (lrow & 31);   // gates 2,3
    Bg1 = (const char*)(Bsel + (size_t)br1 * K) + lseg * 16;
    Bg2 = (const char*)(Bsel + (size_t)br2 * K) + lseg * 16;
  } else {
    biasp = bias0 + bn0;
    Bg1 = (const char*)(B0 + (size_t)(bn0 + lrow) * K) + lseg * 16;
    Bg2 = Bg1 + (size_t)64 * K * 2;
  }
  int w = tid >> 6, l = tid & 63, lm = l & 15, lq = l >> 4;
  int wm = w & 1, wn = w >> 1;
  f32x4 acc[4][4] = {};
  for (int k0 = 0; k0 < K; k0 += 64) {
#pragma unroll
    for (int p = 0; p < 2; p++) {
      g2l16(Ag, (char*)As[p] + tid * 16);
      g2l16(Ag + 4096, (char*)As[p] + 4096 + tid * 16);  // +64 rows = 64*64B
      g2l16(Bg1, (char*)Bs[p] + tid * 16);
      g2l16(Bg2, (char*)Bs[p] + 4096 + tid * 16);
      Ag += Aadv; Bg1 += 64; Bg2 += 64;
    }
    __syncthreads();
#pragma unroll
    for (int p = 0; p < 2; p++) {
      short8 afr[4], bfr[4];
#pragma unroll
      for (int i = 0; i < 4; i++) {
        afr[i] = *(const short8*)&As[p][(wm * 64 + i * 16 + lm) * 32 + lq * 8];
        bfr[i] = *(const short8*)&Bs[p][(wn * 64 + i * 16 + lm) * 32 + lq * 8];
      }
#pragma unroll
      for (int mi = 0; mi < 4; mi++)
#pragma unroll
        for (int ni = 0; ni < 4; ni++) acc[mi][ni] = MFMA16(afr[mi], bfr[ni], acc[mi][ni]);
    }
    __syncthreads();
  }
  float bv[4];
#pragma unroll
  for (int ni = 0; ni < 4; ni++) {
    int cb = wn * 64 + ni * 16 + lm;
    bv[ni] = CPERM ? biasp[(cb >> 5) * 256 + js * 32 + (cb & 31)] : biasp[cb];
  }
#pragma unroll
  for (int mi = 0; mi < 4; mi++)
#pragma unroll
    for (int ni = 0; ni < 4; ni++) {
      int col = bn0 + wn * 64 + ni * 16 + lm;
#pragma unroll
      for (int r = 0; r < 4; r++) {
        size_t row = bm0 + wm * 64 + mi * 16 + lq * 4 + r;
        stc(&C[row * N + col], acc[mi][ni][r] + bv[ni]);
      }
    }
}

// ---- K1b: conv 1x1 GEMM fused with row-softmax+scatter (proven, frozen).
__global__ __launch_bounds__(256) void conv_softmax(
    const bf16_t* __restrict__ A, const bf16_t* __restrict__ B0,
    const float* __restrict__ bias, bf16_t* __restrict__ Wscr, int M, int K) {
  __shared__ __align__(16) short As[2][128 * 32];
  __shared__ __align__(16) short Bs[2][128 * 32];
  __shared__ float part[2][128];
  int tid = threadIdx.x;
  int bm0 = blockIdx.x * 128;
  int lrow = tid >> 2, lseg = tid & 3;
  const char* Ag = (const char*)A + ((size_t)(bm0 + lrow) * 32 + lseg * 8) * 2;
  size_t Aadv = (size_t)M * 64;
  const char* Bg1 = (const char*)(B0 + (size_t)lrow * K) + lseg * 16;
  const char* Bg2 = Bg1 + (size_t)64 * K * 2;
  int w = tid >> 6, l = tid & 63, lm = l & 15, lq = l >> 4;
  int wm = w & 1, wn = w >> 1;
  f32x4 acc[4][4] = {};
  for (int k0 = 0; k0 < K; k0 += 64) {
#pragma unroll
    for (int p = 0; p < 2; p++) {
      g2l16(Ag, (char*)As[p] + tid * 16);
      g2l16(Ag + 4096, (char*)As[p] + 4096 + tid * 16);
      g2l16(Bg1, (char*)Bs[p] + tid * 16);
      g2l16(Bg2, (char*)Bs[p] + 4096 + tid * 16);
      Ag += Aadv; Bg1 += 64; Bg2 += 64;
    }
    __syncthreads();
#pragma unroll
    for (int p = 0; p < 2; p++) {
      short8 afr[4], bfr[4];
#pragma unroll
      for (int i = 0; i < 4; i++) {
        afr[i] = *(const short8*)&As[p][(wm * 64 + i * 16 + lm) * 32 + lq * 8];
        bfr[i] = *(const short8*)&Bs[p][(wn * 64 + i * 16 + lm) * 32 + lq * 8];
      }
#pragma unroll
      for (int mi = 0; mi < 4; mi++)
#pragma unroll
        for (int ni = 0; ni < 4; ni++) acc[mi][ni] = MFMA16(afr[mi], bfr[ni], acc[mi][ni]);
    }
    __syncthreads();
  }
  float bv[4];
  bool vld[4];
#pragma unroll
  for (int ni = 0; ni < 4; ni++) {
    int col = wn * 64 + ni * 16 + lm;
    bv[ni] = bias[col];
    vld[ni] = (col < 100);
  }
  float pmax[4][4];
#pragma unroll
  for (int mi = 0; mi < 4; mi++)
#pragma unroll
    for (int r = 0; r < 4; r++) {
      float m = -1e30f;
#pragma unroll
      for (int ni = 0; ni < 4; ni++)
        if (vld[ni]) m = fmaxf(m, acc[mi][ni][r] + bv[ni]);
      pmax[mi][r] = m;
    }
#pragma unroll
  for (int mask = 1; mask <= 8; mask <<= 1)
#pragma unroll
    for (int mi = 0; mi < 4; mi++)
#pragma unroll
      for (int r = 0; r < 4; r++) pmax[mi][r] = fmaxf(pmax[mi][r], __shfl_xor(pmax[mi][r], mask));
  if (lm == 0)
#pragma unroll
    for (int mi = 0; mi < 4; mi++)
#pragma unroll
      for (int r = 0; r < 4; r++) part[wn][wm * 64 + mi * 16 + lq * 4 + r] = pmax[mi][r];
  __syncthreads();
  float fm[4][4];
#pragma unroll
  for (int mi = 0; mi < 4; mi++)
#pragma unroll
    for (int r = 0; r < 4; r++)
      fm[mi][r] = fmaxf(pmax[mi][r], part[wn ^ 1][wm * 64 + mi * 16 + lq * 4 + r]);
  __syncthreads();
  float ev[4][4][4];
  float ps[4][4];
#pragma unroll
  for (int mi = 0; mi < 4; mi++)
#pragma unroll
    for (int r = 0; r < 4; r++) {
      float s = 0.0f;
#pragma unroll
      for (int ni = 0; ni < 4; ni++) {
        float e = vld[ni] ? __expf(acc[mi][ni][r] + bv[ni] - fm[mi][r]) : 0.0f;
        ev[mi][ni][r] = e;
        s += e;
      }
      ps[mi][r] = s;
    }
#pragma unroll
  for (int mask = 1; mask <= 8; mask <<= 1)
#pragma unroll
    for (int mi = 0; mi < 4; mi++)
#pragma unroll
      for (int r = 0; r < 4; r++) ps[mi][r] += __shfl_xor(ps[mi][r], mask);
  if (lm == 0)
#pragma unroll
    for (int mi = 0; mi < 4; mi++)
#pragma unroll
      for (int r = 0; r < 4; r++) part[wn][wm * 64 + mi * 16 + lq * 4 + r] = ps[mi][r];
  __syncthreads();
#pragma unroll
  for (int mi = 0; mi < 4; mi++)
#pragma unroll
    for (int r = 0; r < 4; r++) {
      float inv =
          1.0f / (ps[mi][r] + part[wn ^ 1][wm * 64 + mi * 16 + lq * 4 + r]);
      int grow = bm0 + wm * 64 + mi * 16 + lq * 4 + r;
      int b = grow / 784, q = grow - b * 784;
      size_t base = (size_t)b * 784 * 128;
#pragma unroll
      for (int ni = 0; ni < 4; ni++) {
        int col = wn * 64 + ni * 16 + lm;
        if (col < 100) {
          int mm = col * 784 + q;
          Wscr[base + (size_t)(mm / 100) * 128 + (mm % 100)] =
              __float2bfloat16(ev[mi][ni][r] * inv);
        }
      }
    }
}

// ---- K2: PERSISTENT 28-step bidirectional LSTM scan, WAVE-AUTONOMOUS sync
// (R7 structure, frozen) + NON-TEMPORAL hints on the zero-reuse streams:
// G gate loads (read-once, 205MB/scan) and outb stores (100MB, consumed next
// kernel) no longer allocate in the Infinity Cache, so the 3.7MB h ping-pong
// buffers stay MALL-resident between the write (step s) and the 8x-amplified
// reads (step s+1) -- targeting the ~95MB of h-read HBM misses in FETCH_SIZE.
// Arithmetic bit-identical; only cache-policy bits change.
__global__ __launch_bounds__(256, 2) void lstm_scan(
    const bf16_t* __restrict__ G, const bf16_t* __restrict__ whh_f,
    const bf16_t* __restrict__ whh_b, bf16_t* __restrict__ hA,
    bf16_t* __restrict__ hB, bf16_t* __restrict__ outb,
    unsigned int* __restrict__ bar) {
  int dir = blockIdx.y;
  int js = blockIdx.x & 7;   // 32-col hidden slice
  int rg = blockIdx.x >> 3;  // 0..27, 64 rows each
  int tid = threadIdx.x, w = tid >> 6, l = tid & 63, lm = l & 15, lq = l >> 4;
  const short* whh = (const short*)(dir ? whh_b : whh_f);
  __shared__ __align__(16) short Ws[128 * 256];  // 64 KB, XOR-swizzled
  __shared__ __align__(16) short ht[64 * 40];    // per-wave 16-row staging slabs
#pragma unroll
  for (int i = 0; i < 16; i++) {
    int segid = i * 256 + tid;  // < 4096
    int row = segid >> 5, seg = segid & 31;
    int gate = row >> 5, jj = row & 31;
    short8 v = *(const short8*)&whh[((size_t)(gate * 256 + js * 32 + jj)) * 256 + seg * 8];
    *(short8*)&Ws[row * 256 + ((seg ^ (row & 7)) * 8)] = v;
  }
  __syncthreads();
  unsigned int* cnt = bar + (((dir * 28 + rg) << 2) + w) * 16;  // own 64B line
  int r0 = rg * 64 + w * 16;  // wave's 16 batch rows
  size_t dbase = (size_t)dir * 458752;  // u16 units: dir slab of h ([8][1792][32])
  const unsigned short* Gb = (const unsigned short*)G + (size_t)dir * 1024 + js * 128;
  float creg[2][4] = {};      // c state, register-resident across all steps
  unsigned short gvs[2][4][4];
  auto load_gvs = [&](int tt) {
#pragma unroll
    for (int nj = 0; nj < 2; nj++)
#pragma unroll
      for (int r = 0; r < 4; r++) {
        int bi = r0 + lq * 4 + r;
        const unsigned short* gp = Gb + ((size_t)bi * 28 + tt) * 2048 + nj * 16 + lm;
#pragma unroll
        for (int gate = 0; gate < 4; gate++)
          gvs[nj][gate][r] = __builtin_nontemporal_load(gp + gate * 32);
      }
  };
  load_gvs(dir ? 27 : 0);
  // store-phase lane mapping: wave w's 64 lanes cover its own 16 rows x 4 segs
  int srow = w * 16 + (l >> 2), sseg = l & 3;
  int sbi = rg * 64 + srow;
  int sbb = sbi / 28, srr = sbi - sbb * 28;
#pragma unroll 1
  for (int s = 0; s < 28; s++) {
    int t = dir ? 27 - s : s;
    f32x4 acc[4][2] = {};
    if (s > 0) {
      unsigned int tgt = 8u * (unsigned)s;
      while (__hip_atomic_load(cnt, __ATOMIC_RELAXED, __HIP_MEMORY_SCOPE_AGENT) < tgt)
        __builtin_amdgcn_s_sleep(1);
      const ull* hrp = (const ull*)((s & 1) ? hA : hB);
      ull hq[8][2];
#pragma unroll
      for (int kk = 0; kk < 8; kk++) {
        size_t off = dbase + (size_t)kk * 57344 + (size_t)(r0 + lm) * 32 + lq * 8;  // u16
        hq[kk][0] =
            __hip_atomic_load(hrp + (off >> 2), __ATOMIC_RELAXED, __HIP_MEMORY_SCOPE_AGENT);
        hq[kk][1] = __hip_atomic_load(hrp + (off >> 2) + 1, __ATOMIC_RELAXED,
                                      __HIP_MEMORY_SCOPE_AGENT);
      }
#pragma unroll
      for (int kk = 0; kk < 8; kk++) {
        short8 a;
        ((ull*)&a)[0] = hq[kk][0];
        ((ull*)&a)[1] = hq[kk][1];
        int bseg = ((kk * 4 + lq) ^ (lm & 7)) * 8;
#pragma unroll
        for (int gate = 0; gate < 4; gate++)
#pragma unroll
          for (int nj = 0; nj < 2; nj++) {
            short8 b = *(const short8*)&Ws[(gate * 32 + nj * 16 + lm) * 256 + bseg];
            acc[gate][nj] = MFMA16(a, b, acc[gate][nj]);
          }
      }
    }
    // gate epilogue -> wave-local ht slab (pure in-wave LDS use, no barrier)
#pragma unroll
    for (int nj = 0; nj < 2; nj++)
#pragma unroll
      for (int r = 0; r < 4; r++) {
        float gi = bf2f(gvs[nj][0][r]) + acc[0][nj][r];
        float gf = bf2f(gvs[nj][1][r]) + acc[1][nj][r];
        float gg = bf2f(gvs[nj][2][r]) + acc[2][nj][r];
        float go = bf2f(gvs[nj][3][r]) + acc[3][nj][r];
        float cn = sigm(gf) * creg[nj][r] + sigm(gi) * tanh_(gg);
        float hn = sigm(go) * tanh_(cn);
        creg[nj][r] = cn;
        ht[(w * 16 + lq * 4 + r) * 40 + nj * 16 + lm] =
            __bfloat16_as_short(__float2bfloat16(hn));
      }
    {  // wave-local coalesced stores: h slab (MALL write-through) + outb (nt)
      u32x4 v = *(const u32x4*)&ht[srow * 40 + sseg * 8];
      ull* hwp = (ull*)((s & 1) ? hB : hA);
      size_t off = dbase + (size_t)js * 57344 + (size_t)sbi * 32 + sseg * 8;  // u16
      ull q0 = ((const ull*)&v)[0];
      ull q1 = ((const ull*)&v)[1];
      __hip_atomic_store(hwp + (off >> 2), q0, __ATOMIC_RELAXED, __HIP_MEMORY_SCOPE_AGENT);
      __hip_atomic_store(hwp + (off >> 2) + 1, q1, __ATOMIC_RELAXED,
                         __HIP_MEMORY_SCOPE_AGENT);
      short* ob = (short*)outb + (size_t)(dir * 8 + js) * NROW * 32;
      ull* op = (ull*)&ob[((size_t)sbb * 784 + (size_t)t * 28 + srr) * 32 + sseg * 8];
      __builtin_nontemporal_store(q0, op);
      __builtin_nontemporal_store(q1, op + 1);
    }
    if (s < 27) {
      // drain THIS WAVE's stores (vmcnt is wave-local), publish, then prefetch
      asm volatile("s_waitcnt vmcnt(0)" ::: "memory");
      if (l == 0)
        __hip_atomic_fetch_add(cnt, 1u, __ATOMIC_RELAXED, __HIP_MEMORY_SCOPE_AGENT);
      load_gvs(dir ? 26 - s : s + 1);  // flies during the next poll
    }
  }
}

// ---- K4: per-b GEMM out[p,c] = sum_k Wscr[b][p][k] * xs[b][c][k]  (K=128 padded;
// Wscr pad cols finite garbage, xs pad cols explicit zeros -> product 0). Output fp32.
__global__ __launch_bounds__(256) void final_gemm(const bf16_t* __restrict__ Wscr,
                                                  const bf16_t* __restrict__ xs,
                                                  float* __restrict__ outp) {
  int m0 = blockIdx.x * 112, n0 = blockIdx.y * 128, b = blockIdx.z;
  int tid = threadIdx.x, w = tid >> 6, l = tid & 63, lm = l & 15, lq = l >> 4;
  const short* Ab = (const short*)Wscr + (size_t)b * 784 * 128;
  const short* Bb = (const short*)xs + (size_t)b * 512 * 128;
  f32x4 acc[7][2] = {};
#pragma unroll
  for (int kk = 0; kk < 4; kk++) {
    short8 b0 = *(const short8*)&Bb[(size_t)(n0 + w * 32 + lm) * 128 + kk * 32 + lq * 8];
    short8 b1 = *(const short8*)&Bb[(size_t)(n0 + w * 32 + 16 + lm) * 128 + kk * 32 + lq * 8];
#pragma unroll
    for (int mi = 0; mi < 7; mi++) {
      short8 a = *(const short8*)&Ab[(size_t)(m0 + mi * 16 + lm) * 128 + kk * 32 + lq * 8];
      acc[mi][0] = MFMA16(a, b0, acc[mi][0]);
      acc[mi][1] = MFMA16(a, b1, acc[mi][1]);
    }
  }
#pragma unroll
  for (int mi = 0; mi < 7; mi++)
#pragma unroll
    for (int ni = 0; ni < 2; ni++) {
      int c = n0 + w * 32 + ni * 16 + lm;
#pragma unroll
      for (int r = 0; r < 4; r++) {
        int p = m0 + mi * 16 + lq * 4 + r;
        outp[(size_t)b * 401408 + (size_t)p * 512 + c] = acc[mi][ni][r];
      }
    }
}

extern "C" void kernel_launch(void* const* d_in, const int* in_sizes, int n_in,
                              void* d_out, int out_size, void* d_ws, size_t ws_size,
                              hipStream_t stream) {
  const float* x = (const float*)d_in[0];
  const float* v_wih_f = (const float*)d_in[1];
  const float* v_whh_f = (const float*)d_in[2];
  const float* v_b_f = (const float*)d_in[3];
  const float* v_wih_b = (const float*)d_in[4];
  const float* v_whh_b = (const float*)d_in[5];
  const float* v_b_b = (const float*)d_in[6];
  const float* h_wih_f = (const float*)d_in[7];
  const float* h_whh_f = (const float*)d_in[8];
  const float* h_b_f = (const float*)d_in[9];
  const float* h_wih_b = (const float*)d_in[10];
  const float* h_whh_b = (const float*)d_in[11];
  const float* h_b_b = (const float*)d_in[12];
  const float* conv_w = (const float*)d_in[13];
  const float* conv_b = (const float*)d_in[14];

  // workspace carve (~329 MB): Wscr aliases G (G dead after horizontal scan).
  // h ping-pong buffer #2 aliases dead regions: Xin during vertical scan,
  // Vout during horizontal scan. Old cstate slot hosts the flag counters.
  char* ws = (char*)d_ws;
  bf16_t* Xin = (bf16_t*)(ws);                  // 51,380,224 B (aliased as Hout later)
  bf16_t* Vout = (bf16_t*)(ws + 51380224);      // 51,380,224
  bf16_t* G = (bf16_t*)(ws + 102760448);        // 205,520,896
  bf16_t* Wscr = (bf16_t*)(ws + 128450560);     // 12,845,056 (alias of G)
  bf16_t* xs = (bf16_t*)(ws + 308281344);       // 8,388,608
  bf16_t* cwp = (bf16_t*)(ws + 316669952);      // 131,072
  float* cbp = (float*)(ws + 316801024);        // 512
  bf16_t* hstate = (bf16_t*)(ws + 316801536);   // 1,835,008 (h ping buffer A)
  unsigned int* bar = (unsigned int*)(ws + 318636544);  // 2 scans x 3584 u32 flags
  bf16_t* wvf = (bf16_t*)(ws + 322306560);      // v_wih_f bf16: 1,048,576
  bf16_t* wvb = (bf16_t*)(ws + 323355136);      // v_wih_b bf16: 1,048,576
  bf16_t* uvf = (bf16_t*)(ws + 324403712);      // v_whh_f bf16: 524,288
  bf16_t* uvb = (bf16_t*)(ws + 324928000);      // v_whh_b bf16: 524,288
  bf16_t* whf = (bf16_t*)(ws + 325452288);      // h_wih_f bf16: 1,048,576
  bf16_t* whb = (bf16_t*)(ws + 326500864);      // h_wih_b bf16: 1,048,576
  bf16_t* uhf = (bf16_t*)(ws + 327549440);      // h_whh_f bf16: 524,288
  bf16_t* uhb = (bf16_t*)(ws + 328073728);      // h_whh_b bf16: 524,288
  bf16_t* Hout = Xin;

  CvtArgs ca;
  ca.src[0] = v_wih_f; ca.dst[0] = wvf; ca.n[0] = 524288;
  ca.src[1] = v_wih_b; ca.dst[1] = wvb; ca.n[1] = 524288;
  ca.src[2] = v_whh_f; ca.dst[2] = uvf; ca.n[2] = 262144;
  ca.src[3] = v_whh_b; ca.dst[3] = uvb; ca.n[3] = 262144;
  ca.src[4] = h_wih_f; ca.dst[4] = whf; ca.n[4] = 524288;
  ca.src[5] = h_wih_b; ca.dst[5] = whb; ca.n[5] = 524288;
  ca.src[6] = h_whh_f; ca.dst[6] = uhf; ca.n[6] = 262144;
  ca.src[7] = h_whh_b; ca.dst[7] = uhb; ca.n[7] = 262144;
  cvt_all<<<dim3(2048, 8), 256, 0, stream>>>(ca);

  transpose_x<<<dim3(4, 28, 64), 256, 0, stream>>>(x, Xin, xs);
  pad_conv<<<dim3(128), 128, 0, stream>>>(conv_w, conv_b, cwp, cbp, bar);

  // vertical stage: G = Xin @ [Wf;Wb]^T + bias (cols G-permuted); persistent scan
  gemm_bt<bf16_t, true><<<dim3(16, 392), 256, 0, stream>>>(
      Xin, wvf, wvb, v_b_f, v_b_b, G, NROW, 2048, 512);
  lstm_scan<<<dim3(224, 2), 256, 0, stream>>>(G, uvf, uvb, hstate, Xin, Vout, bar);

  // horizontal stage
  gemm_bt<bf16_t, true><<<dim3(16, 392), 256, 0, stream>>>(
      Vout, whf, whb, h_b_f, h_b_b, G, NROW, 2048, 512);
  lstm_scan<<<dim3(224, 2), 256, 0, stream>>>(G, uhf, uhb, hstate, Vout, Hout, bar + 3584);

  // fused 1x1 conv + softmax + scatter, then final attention GEMM
  conv_softmax<<<dim3(392), 256, 0, stream>>>(Hout, cwp, cbp, Wscr, NROW, 512);
  final_gemm<<<dim3(7, 4, 64), 256, 0, stream>>>(Wscr, xs, (float*)d_out);
}

// Round 14
// 939.867 us; speedup vs baseline: 1.0702x; 1.0702x over previous
//
#include <hip/hip_runtime.h>
#include <hip/hip_bf16.h>
#include <stdint.h>

typedef __hip_bfloat16 bf16_t;
typedef __attribute__((ext_vector_type(8))) short short8;
typedef __attribute__((ext_vector_type(4))) float f32x4;
typedef __attribute__((ext_vector_type(4))) unsigned int u32x4;
typedef unsigned long long ull;

#define MFMA16(a, b, c) __builtin_amdgcn_mfma_f32_16x16x32_bf16(a, b, c, 0, 0, 0)

#define NROW 50176   // B*S*S
#define NBATCH 1792  // B*S

__device__ __forceinline__ void g2l16(const void* g, void* l) {
  __builtin_amdgcn_global_load_lds(
      (const __attribute__((address_space(1))) unsigned int*)g,
      (__attribute__((address_space(3))) unsigned int*)l, 16, 0, 0);
}
__device__ __forceinline__ float sigm(float x) { return 1.0f / (1.0f + __expf(-x)); }
__device__ __forceinline__ float tanh_(float x) { return 2.0f / (1.0f + __expf(-2.0f * x)) - 1.0f; }
__device__ __forceinline__ void stc(bf16_t* p, float v) { *p = __float2bfloat16(v); }
__device__ __forceinline__ void stc(float* p, float v) { *p = v; }
__device__ __forceinline__ float bf2f(unsigned short u) {
  return __uint_as_float((unsigned int)u << 16);
}

// ---- fp32 -> bf16 conversion of all 8 LSTM weight matrices in one launch
struct CvtArgs {
  const float* src[8];
  bf16_t* dst[8];
  int n[8];
};
__global__ void cvt_all(CvtArgs a) {
  int arr = blockIdx.y;
  int i = blockIdx.x * 256 + threadIdx.x;
  if (i < a.n[arr]) a.dst[arr][i] = __float2bfloat16(a.src[arr][i]);
}

// ---- K0a: x fp32 [B,512,28,28] -> Xin K-grouped [16][50176][32] bf16
// FUSED: also emits x_s[b][c][k] = x[b][c][3kh][3kw] for rows h = 3kh (the tile
// already holds them), and zero-pads k in [100,128) once (h==0 blocks).
__global__ void transpose_x(const float* __restrict__ x, bf16_t* __restrict__ Xin,
                            bf16_t* __restrict__ xs) {
  int c0 = blockIdx.x * 128, h = blockIdx.y, b = blockIdx.z;
  __shared__ __align__(16) short tile[128 * 29];
  const float* xb = x + ((size_t)b * 512 + c0) * 784 + h * 28;
  for (int e = threadIdx.x; e < 128 * 28; e += 256) {
    int cc = e / 28, w = e - cc * 28;
    tile[cc * 29 + w] = __bfloat16_as_short(__float2bfloat16(xb[(size_t)cc * 784 + w]));
  }
  __syncthreads();
  size_t orow0 = (size_t)(b * 28 + h) * 28;
  short* os = (short*)Xin;
  for (int e = threadIdx.x; e < 28 * 128; e += 256) {
    int w = e >> 7, cc = e & 127;
    int c = c0 + cc;
    os[(size_t)(c >> 5) * NROW * 32 + (orow0 + w) * 32 + (c & 31)] = tile[cc * 29 + w];
  }
  short* xss = (short*)xs;
  if (h % 3 == 0) {  // h in {0,3,...,27} -> kh = h/3 in 0..9
    int kh = h / 3;
    for (int e = threadIdx.x; e < 1280; e += 256) {
      int cc = e / 10, kw = e - cc * 10;
      xss[((size_t)(b * 512) + c0 + cc) * 128 + kh * 10 + kw] = tile[cc * 29 + 3 * kw];
    }
  }
  if (h == 0) {  // zero pad cols 100..127
    for (int e = threadIdx.x; e < 128 * 28; e += 256) {
      int cc = e / 28, kp = e - cc * 28;
      xss[((size_t)(b * 512) + c0 + cc) * 128 + 100 + kp] = 0;
    }
  }
}

// ---- K0c: pad conv_w fp32 [100,512] -> bf16 [128,512]; conv_b fp32 [100] -> fp32 [128]
//      also zero the per-(group,wave) flag counters (2 scans x 3584 u32)
__global__ void pad_conv(const float* __restrict__ cw, const float* __restrict__ cb,
                         bf16_t* __restrict__ cwp, float* __restrict__ cbp,
                         unsigned int* __restrict__ bar) {
  int r = blockIdx.x;  // 128
  if (r == 0)
    for (int i = threadIdx.x; i < 7168; i += 128) bar[i] = 0;
  for (int i = threadIdx.x; i < 512; i += 128)
    cwp[r * 512 + i] = __float2bfloat16((r < 100) ? cw[r * 512 + i] : 0.0f);
  if (r == 0) cbp[threadIdx.x] = (threadIdx.x < 100) ? cb[threadIdx.x] : 0.0f;
}

// ---- K1 (best-measured structure): C[M,Nphys] = A[M,K] @ Bsel^T + bias.
// A is K-grouped [K/32][M][32] (8KB contiguous per 128x32 tile). CPERM: output
// cols permuted to dir*1024 + js*128 + gate*32 + jj (lstm-block-local 256B/row);
// B rows consumed in (gate,jj) order, bias index-remapped; C-store addresses
// contiguous. BK=64: two k-group panels per barrier pair -> 32 MFMA between
// barriers. Panel row stride 64B (free 2-way bank aliasing).
template <typename CT, bool CPERM>
__global__ __launch_bounds__(256) void gemm_bt(
    const bf16_t* __restrict__ A, const bf16_t* __restrict__ B0,
    const bf16_t* __restrict__ B1, const float* __restrict__ bias0,
    const float* __restrict__ bias1, CT* __restrict__ C, int M, int N, int K) {
  __shared__ __align__(16) short As[2][128 * 32];
  __shared__ __align__(16) short Bs[2][128 * 32];
  int tid = threadIdx.x;
  int nb = blockIdx.x;
  int bm0 = blockIdx.y * 128, bn0 = nb * 128;
  int lrow = tid >> 2, lseg = tid & 3;  // 4 threads x 16B cover one 32-elem row
  const char* Ag = (const char*)A + ((size_t)(bm0 + lrow) * 32 + lseg * 8) * 2;
  size_t Aadv = (size_t)M * 64;
  const float* biasp;
  const char *Bg1, *Bg2;
  int js = 0;
  if (CPERM) {
    int dir = nb >> 3;
    js = nb & 7;
    const bf16_t* Bsel = dir ? B1 : B0;
    biasp = dir ? bias1 : bias0;
    int br1 = (lrow >> 5) * 256 + js * 32 + (lrow & 31);          // gates 0,1
    int br2 = ((lrow + 64) >> 5) * 256 + js * 32 + (lrow & 31);   // gates 2,3
    Bg1 = (const char*)(Bsel + (size_t)br1 * K) + lseg * 16;
    Bg2 = (const char*)(Bsel + (size_t)br2 * K) + lseg * 16;
  } else {
    biasp = bias0 + bn0;
    Bg1 = (const char*)(B0 + (size_t)(bn0 + lrow) * K) + lseg * 16;
    Bg2 = Bg1 + (size_t)64 * K * 2;
  }
  int w = tid >> 6, l = tid & 63, lm = l & 15, lq = l >> 4;
  int wm = w & 1, wn = w >> 1;
  f32x4 acc[4][4] = {};
  for (int k0 = 0; k0 < K; k0 += 64) {
#pragma unroll
    for (int p = 0; p < 2; p++) {
      g2l16(Ag, (char*)As[p] + tid * 16);
      g2l16(Ag + 4096, (char*)As[p] + 4096 + tid * 16);  // +64 rows = 64*64B
      g2l16(Bg1, (char*)Bs[p] + tid * 16);
      g2l16(Bg2, (char*)Bs[p] + 4096 + tid * 16);
      Ag += Aadv; Bg1 += 64; Bg2 += 64;
    }
    __syncthreads();
#pragma unroll
    for (int p = 0; p < 2; p++) {
      short8 afr[4], bfr[4];
#pragma unroll
      for (int i = 0; i < 4; i++) {
        afr[i] = *(const short8*)&As[p][(wm * 64 + i * 16 + lm) * 32 + lq * 8];
        bfr[i] = *(const short8*)&Bs[p][(wn * 64 + i * 16 + lm) * 32 + lq * 8];
      }
#pragma unroll
      for (int mi = 0; mi < 4; mi++)
#pragma unroll
        for (int ni = 0; ni < 4; ni++) acc[mi][ni] = MFMA16(afr[mi], bfr[ni], acc[mi][ni]);
    }
    __syncthreads();
  }
  float bv[4];
#pragma unroll
  for (int ni = 0; ni < 4; ni++) {
    int cb = wn * 64 + ni * 16 + lm;
    bv[ni] = CPERM ? biasp[(cb >> 5) * 256 + js * 32 + (cb & 31)] : biasp[cb];
  }
#pragma unroll
  for (int mi = 0; mi < 4; mi++)
#pragma unroll
    for (int ni = 0; ni < 4; ni++) {
      int col = bn0 + wn * 64 + ni * 16 + lm;
#pragma unroll
      for (int r = 0; r < 4; r++) {
        size_t row = bm0 + wm * 64 + mi * 16 + lq * 4 + r;
        stc(&C[row * N + col], acc[mi][ni][r] + bv[ni]);
      }
    }
}

// ---- K1b: conv 1x1 GEMM fused with row-softmax+scatter (proven, frozen).
__global__ __launch_bounds__(256) void conv_softmax(
    const bf16_t* __restrict__ A, const bf16_t* __restrict__ B0,
    const float* __restrict__ bias, bf16_t* __restrict__ Wscr, int M, int K) {
  __shared__ __align__(16) short As[2][128 * 32];
  __shared__ __align__(16) short Bs[2][128 * 32];
  __shared__ float part[2][128];
  int tid = threadIdx.x;
  int bm0 = blockIdx.x * 128;
  int lrow = tid >> 2, lseg = tid & 3;
  const char* Ag = (const char*)A + ((size_t)(bm0 + lrow) * 32 + lseg * 8) * 2;
  size_t Aadv = (size_t)M * 64;
  const char* Bg1 = (const char*)(B0 + (size_t)lrow * K) + lseg * 16;
  const char* Bg2 = Bg1 + (size_t)64 * K * 2;
  int w = tid >> 6, l = tid & 63, lm = l & 15, lq = l >> 4;
  int wm = w & 1, wn = w >> 1;
  f32x4 acc[4][4] = {};
  for (int k0 = 0; k0 < K; k0 += 64) {
#pragma unroll
    for (int p = 0; p < 2; p++) {
      g2l16(Ag, (char*)As[p] + tid * 16);
      g2l16(Ag + 4096, (char*)As[p] + 4096 + tid * 16);
      g2l16(Bg1, (char*)Bs[p] + tid * 16);
      g2l16(Bg2, (char*)Bs[p] + 4096 + tid * 16);
      Ag += Aadv; Bg1 += 64; Bg2 += 64;
    }
    __syncthreads();
#pragma unroll
    for (int p = 0; p < 2; p++) {
      short8 afr[4], bfr[4];
#pragma unroll
      for (int i = 0; i < 4; i++) {
        afr[i] = *(const short8*)&As[p][(wm * 64 + i * 16 + lm) * 32 + lq * 8];
        bfr[i] = *(const short8*)&Bs[p][(wn * 64 + i * 16 + lm) * 32 + lq * 8];
      }
#pragma unroll
      for (int mi = 0; mi < 4; mi++)
#pragma unroll
        for (int ni = 0; ni < 4; ni++) acc[mi][ni] = MFMA16(afr[mi], bfr[ni], acc[mi][ni]);
    }
    __syncthreads();
  }
  float bv[4];
  bool vld[4];
#pragma unroll
  for (int ni = 0; ni < 4; ni++) {
    int col = wn * 64 + ni * 16 + lm;
    bv[ni] = bias[col];
    vld[ni] = (col < 100);
  }
  float pmax[4][4];
#pragma unroll
  for (int mi = 0; mi < 4; mi++)
#pragma unroll
    for (int r = 0; r < 4; r++) {
      float m = -1e30f;
#pragma unroll
      for (int ni = 0; ni < 4; ni++)
        if (vld[ni]) m = fmaxf(m, acc[mi][ni][r] + bv[ni]);
      pmax[mi][r] = m;
    }
#pragma unroll
  for (int mask = 1; mask <= 8; mask <<= 1)
#pragma unroll
    for (int mi = 0; mi < 4; mi++)
#pragma unroll
      for (int r = 0; r < 4; r++) pmax[mi][r] = fmaxf(pmax[mi][r], __shfl_xor(pmax[mi][r], mask));
  if (lm == 0)
#pragma unroll
    for (int mi = 0; mi < 4; mi++)
#pragma unroll
      for (int r = 0; r < 4; r++) part[wn][wm * 64 + mi * 16 + lq * 4 + r] = pmax[mi][r];
  __syncthreads();
  float fm[4][4];
#pragma unroll
  for (int mi = 0; mi < 4; mi++)
#pragma unroll
    for (int r = 0; r < 4; r++)
      fm[mi][r] = fmaxf(pmax[mi][r], part[wn ^ 1][wm * 64 + mi * 16 + lq * 4 + r]);
  __syncthreads();
  float ev[4][4][4];
  float ps[4][4];
#pragma unroll
  for (int mi = 0; mi < 4; mi++)
#pragma unroll
    for (int r = 0; r < 4; r++) {
      float s = 0.0f;
#pragma unroll
      for (int ni = 0; ni < 4; ni++) {
        float e = vld[ni] ? __expf(acc[mi][ni][r] + bv[ni] - fm[mi][r]) : 0.0f;
        ev[mi][ni][r] = e;
        s += e;
      }
      ps[mi][r] = s;
    }
#pragma unroll
  for (int mask = 1; mask <= 8; mask <<= 1)
#pragma unroll
    for (int mi = 0; mi < 4; mi++)
#pragma unroll
      for (int r = 0; r < 4; r++) ps[mi][r] += __shfl_xor(ps[mi][r], mask);
  if (lm == 0)
#pragma unroll
    for (int mi = 0; mi < 4; mi++)
#pragma unroll
      for (int r = 0; r < 4; r++) part[wn][wm * 64 + mi * 16 + lq * 4 + r] = ps[mi][r];
  __syncthreads();
#pragma unroll
  for (int mi = 0; mi < 4; mi++)
#pragma unroll
    for (int r = 0; r < 4; r++) {
      float inv =
          1.0f / (ps[mi][r] + part[wn ^ 1][wm * 64 + mi * 16 + lq * 4 + r]);
      int grow = bm0 + wm * 64 + mi * 16 + lq * 4 + r;
      int b = grow / 784, q = grow - b * 784;
      size_t base = (size_t)b * 784 * 128;
#pragma unroll
      for (int ni = 0; ni < 4; ni++) {
        int col = wn * 64 + ni * 16 + lm;
        if (col < 100) {
          int mm = col * 784 + q;
          Wscr[base + (size_t)(mm / 100) * 128 + (mm % 100)] =
              __float2bfloat16(ev[mi][ni][r] * inv);
        }
      }
    }
}

// ---- K2 (R7-exact, frozen): PERSISTENT 28-step bidirectional LSTM scan,
// WAVE-AUTONOMOUS sync. Sync per (group,wave) flag with 8 contributors, no
// __syncthreads in the step loop. h via RELAXED agent-scope atomics
// (MALL-coherent); weights LDS-resident; c in registers. 448 blocks resident.
// (R13's nontemporal hints on G/outb REGRESSED 188->210us, FETCH unchanged ->
//  h misses are not MALL-eviction-driven; reverted to plain cached accesses.)
__global__ __launch_bounds__(256, 2) void lstm_scan(
    const bf16_t* __restrict__ G, const bf16_t* __restrict__ whh_f,
    const bf16_t* __restrict__ whh_b, bf16_t* __restrict__ hA,
    bf16_t* __restrict__ hB, bf16_t* __restrict__ outb,
    unsigned int* __restrict__ bar) {
  int dir = blockIdx.y;
  int js = blockIdx.x & 7;   // 32-col hidden slice
  int rg = blockIdx.x >> 3;  // 0..27, 64 rows each
  int tid = threadIdx.x, w = tid >> 6, l = tid & 63, lm = l & 15, lq = l >> 4;
  const short* whh = (const short*)(dir ? whh_b : whh_f);
  __shared__ __align__(16) short Ws[128 * 256];  // 64 KB, XOR-swizzled
  __shared__ __align__(16) short ht[64 * 40];    // per-wave 16-row staging slabs
#pragma unroll
  for (int i = 0; i < 16; i++) {
    int segid = i * 256 + tid;  // < 4096
    int row = segid >> 5, seg = segid & 31;
    int gate = row >> 5, jj = row & 31;
    short8 v = *(const short8*)&whh[((size_t)(gate * 256 + js * 32 + jj)) * 256 + seg * 8];
    *(short8*)&Ws[row * 256 + ((seg ^ (row & 7)) * 8)] = v;
  }
  __syncthreads();
  unsigned int* cnt = bar + (((dir * 28 + rg) << 2) + w) * 16;  // own 64B line
  int r0 = rg * 64 + w * 16;  // wave's 16 batch rows
  size_t dbase = (size_t)dir * 458752;  // u16 units: dir slab of h ([8][1792][32])
  const unsigned short* Gb = (const unsigned short*)G + (size_t)dir * 1024 + js * 128;
  float creg[2][4] = {};      // c state, register-resident across all steps
  unsigned short gvs[2][4][4];
  auto load_gvs = [&](int tt) {
#pragma unroll
    for (int nj = 0; nj < 2; nj++)
#pragma unroll
      for (int r = 0; r < 4; r++) {
        int bi = r0 + lq * 4 + r;
        const unsigned short* gp = Gb + ((size_t)bi * 28 + tt) * 2048 + nj * 16 + lm;
#pragma unroll
        for (int gate = 0; gate < 4; gate++) gvs[nj][gate][r] = gp[gate * 32];
      }
  };
  load_gvs(dir ? 27 : 0);
  // store-phase lane mapping: wave w's 64 lanes cover its own 16 rows x 4 segs
  int srow = w * 16 + (l >> 2), sseg = l & 3;
  int sbi = rg * 64 + srow;
  int sbb = sbi / 28, srr = sbi - sbb * 28;
#pragma unroll 1
  for (int s = 0; s < 28; s++) {
    int t = dir ? 27 - s : s;
    f32x4 acc[4][2] = {};
    if (s > 0) {
      unsigned int tgt = 8u * (unsigned)s;
      while (__hip_atomic_load(cnt, __ATOMIC_RELAXED, __HIP_MEMORY_SCOPE_AGENT) < tgt)
        __builtin_amdgcn_s_sleep(1);
      const ull* hrp = (const ull*)((s & 1) ? hA : hB);
      ull hq[8][2];
#pragma unroll
      for (int kk = 0; kk < 8; kk++) {
        size_t off = dbase + (size_t)kk * 57344 + (size_t)(r0 + lm) * 32 + lq * 8;  // u16
        hq[kk][0] =
            __hip_atomic_load(hrp + (off >> 2), __ATOMIC_RELAXED, __HIP_MEMORY_SCOPE_AGENT);
        hq[kk][1] = __hip_atomic_load(hrp + (off >> 2) + 1, __ATOMIC_RELAXED,
                                      __HIP_MEMORY_SCOPE_AGENT);
      }
#pragma unroll
      for (int kk = 0; kk < 8; kk++) {
        short8 a;
        ((ull*)&a)[0] = hq[kk][0];
        ((ull*)&a)[1] = hq[kk][1];
        int bseg = ((kk * 4 + lq) ^ (lm & 7)) * 8;
#pragma unroll
        for (int gate = 0; gate < 4; gate++)
#pragma unroll
          for (int nj = 0; nj < 2; nj++) {
            short8 b = *(const short8*)&Ws[(gate * 32 + nj * 16 + lm) * 256 + bseg];
            acc[gate][nj] = MFMA16(a, b, acc[gate][nj]);
          }
      }
    }
    // gate epilogue -> wave-local ht slab (pure in-wave LDS use, no barrier)
#pragma unroll
    for (int nj = 0; nj < 2; nj++)
#pragma unroll
      for (int r = 0; r < 4; r++) {
        float gi = bf2f(gvs[nj][0][r]) + acc[0][nj][r];
        float gf = bf2f(gvs[nj][1][r]) + acc[1][nj][r];
        float gg = bf2f(gvs[nj][2][r]) + acc[2][nj][r];
        float go = bf2f(gvs[nj][3][r]) + acc[3][nj][r];
        float cn = sigm(gf) * creg[nj][r] + sigm(gi) * tanh_(gg);
        float hn = sigm(go) * tanh_(cn);
        creg[nj][r] = cn;
        ht[(w * 16 + lq * 4 + r) * 40 + nj * 16 + lm] =
            __bfloat16_as_short(__float2bfloat16(hn));
      }
    {  // wave-local coalesced stores: h slab (MALL write-through) + outb (cached)
      u32x4 v = *(const u32x4*)&ht[srow * 40 + sseg * 8];
      ull* hwp = (ull*)((s & 1) ? hB : hA);
      size_t off = dbase + (size_t)js * 57344 + (size_t)sbi * 32 + sseg * 8;  // u16
      ull q0 = ((const ull*)&v)[0];
      ull q1 = ((const ull*)&v)[1];
      __hip_atomic_store(hwp + (off >> 2), q0, __ATOMIC_RELAXED, __HIP_MEMORY_SCOPE_AGENT);
      __hip_atomic_store(hwp + (off >> 2) + 1, q1, __ATOMIC_RELAXED,
                         __HIP_MEMORY_SCOPE_AGENT);
      short* ob = (short*)outb + (size_t)(dir * 8 + js) * NROW * 32;
      *(u32x4*)&ob[((size_t)sbb * 784 + (size_t)t * 28 + srr) * 32 + sseg * 8] = v;
    }
    if (s < 27) {
      // drain THIS WAVE's stores (vmcnt is wave-local), publish, then prefetch
      asm volatile("s_waitcnt vmcnt(0)" ::: "memory");
      if (l == 0)
        __hip_atomic_fetch_add(cnt, 1u, __ATOMIC_RELAXED, __HIP_MEMORY_SCOPE_AGENT);
      load_gvs(dir ? 26 - s : s + 1);  // flies during the next poll
    }
  }
}

// ---- K4: per-b GEMM out[p,c] = sum_k Wscr[b][p][k] * xs[b][c][k]  (K=128 padded;
// Wscr pad cols finite garbage, xs pad cols explicit zeros -> product 0). Output fp32.
__global__ __launch_bounds__(256) void final_gemm(const bf16_t* __restrict__ Wscr,
                                                  const bf16_t* __restrict__ xs,
                                                  float* __restrict__ outp) {
  int m0 = blockIdx.x * 112, n0 = blockIdx.y * 128, b = blockIdx.z;
  int tid = threadIdx.x, w = tid >> 6, l = tid & 63, lm = l & 15, lq = l >> 4;
  const short* Ab = (const short*)Wscr + (size_t)b * 784 * 128;
  const short* Bb = (const short*)xs + (size_t)b * 512 * 128;
  f32x4 acc[7][2] = {};
#pragma unroll
  for (int kk = 0; kk < 4; kk++) {
    short8 b0 = *(const short8*)&Bb[(size_t)(n0 + w * 32 + lm) * 128 + kk * 32 + lq * 8];
    short8 b1 = *(const short8*)&Bb[(size_t)(n0 + w * 32 + 16 + lm) * 128 + kk * 32 + lq * 8];
#pragma unroll
    for (int mi = 0; mi < 7; mi++) {
      short8 a = *(const short8*)&Ab[(size_t)(m0 + mi * 16 + lm) * 128 + kk * 32 + lq * 8];
      acc[mi][0] = MFMA16(a, b0, acc[mi][0]);
      acc[mi][1] = MFMA16(a, b1, acc[mi][1]);
    }
  }
#pragma unroll
  for (int mi = 0; mi < 7; mi++)
#pragma unroll
    for (int ni = 0; ni < 2; ni++) {
      int c = n0 + w * 32 + ni * 16 + lm;
#pragma unroll
      for (int r = 0; r < 4; r++) {
        int p = m0 + mi * 16 + lq * 4 + r;
        outp[(size_t)b * 401408 + (size_t)p * 512 + c] = acc[mi][ni][r];
      }
    }
}

extern "C" void kernel_launch(void* const* d_in, const int* in_sizes, int n_in,
                              void* d_out, int out_size, void* d_ws, size_t ws_size,
                              hipStream_t stream) {
  const float* x = (const float*)d_in[0];
  const float* v_wih_f = (const float*)d_in[1];
  const float* v_whh_f = (const float*)d_in[2];
  const float* v_b_f = (const float*)d_in[3];
  const float* v_wih_b = (const float*)d_in[4];
  const float* v_whh_b = (const float*)d_in[5];
  const float* v_b_b = (const float*)d_in[6];
  const float* h_wih_f = (const float*)d_in[7];
  const float* h_whh_f = (const float*)d_in[8];
  const float* h_b_f = (const float*)d_in[9];
  const float* h_wih_b = (const float*)d_in[10];
  const float* h_whh_b = (const float*)d_in[11];
  const float* h_b_b = (const float*)d_in[12];
  const float* conv_w = (const float*)d_in[13];
  const float* conv_b = (const float*)d_in[14];

  // workspace carve (~329 MB): Wscr aliases G (G dead after horizontal scan).
  // h ping-pong buffer #2 aliases dead regions: Xin during vertical scan,
  // Vout during horizontal scan. Old cstate slot hosts the flag counters.
  char* ws = (char*)d_ws;
  bf16_t* Xin = (bf16_t*)(ws);                  // 51,380,224 B (aliased as Hout later)
  bf16_t* Vout = (bf16_t*)(ws + 51380224);      // 51,380,224
  bf16_t* G = (bf16_t*)(ws + 102760448);        // 205,520,896
  bf16_t* Wscr = (bf16_t*)(ws + 128450560);     // 12,845,056 (alias of G)
  bf16_t* xs = (bf16_t*)(ws + 308281344);       // 8,388,608
  bf16_t* cwp = (bf16_t*)(ws + 316669952);      // 131,072
  float* cbp = (float*)(ws + 316801024);        // 512
  bf16_t* hstate = (bf16_t*)(ws + 316801536);   // 1,835,008 (h ping buffer A)
  unsigned int* bar = (unsigned int*)(ws + 318636544);  // 2 scans x 3584 u32 flags
  bf16_t* wvf = (bf16_t*)(ws + 322306560);      // v_wih_f bf16: 1,048,576
  bf16_t* wvb = (bf16_t*)(ws + 323355136);      // v_wih_b bf16: 1,048,576
  bf16_t* uvf = (bf16_t*)(ws + 324403712);      // v_whh_f bf16: 524,288
  bf16_t* uvb = (bf16_t*)(ws + 324928000);      // v_whh_b bf16: 524,288
  bf16_t* whf = (bf16_t*)(ws + 325452288);      // h_wih_f bf16: 1,048,576
  bf16_t* whb = (bf16_t*)(ws + 326500864);      // h_wih_b bf16: 1,048,576
  bf16_t* uhf = (bf16_t*)(ws + 327549440);      // h_whh_f bf16: 524,288
  bf16_t* uhb = (bf16_t*)(ws + 328073728);      // h_whh_b bf16: 524,288
  bf16_t* Hout = Xin;

  CvtArgs ca;
  ca.src[0] = v_wih_f; ca.dst[0] = wvf; ca.n[0] = 524288;
  ca.src[1] = v_wih_b; ca.dst[1] = wvb; ca.n[1] = 524288;
  ca.src[2] = v_whh_f; ca.dst[2] = uvf; ca.n[2] = 262144;
  ca.src[3] = v_whh_b; ca.dst[3] = uvb; ca.n[3] = 262144;
  ca.src[4] = h_wih_f; ca.dst[4] = whf; ca.n[4] = 524288;
  ca.src[5] = h_wih_b; ca.dst[5] = whb; ca.n[5] = 524288;
  ca.src[6] = h_whh_f; ca.dst[6] = uhf; ca.n[6] = 262144;
  ca.src[7] = h_whh_b; ca.dst[7] = uhb; ca.n[7] = 262144;
  cvt_all<<<dim3(2048, 8), 256, 0, stream>>>(ca);

  transpose_x<<<dim3(4, 28, 64), 256, 0, stream>>>(x, Xin, xs);
  pad_conv<<<dim3(128), 128, 0, stream>>>(conv_w, conv_b, cwp, cbp, bar);

  // vertical stage: G = Xin @ [Wf;Wb]^T + bias (cols G-permuted); persistent scan
  gemm_bt<bf16_t, true><<<dim3(16, 392), 256, 0, stream>>>(
      Xin, wvf, wvb, v_b_f, v_b_b, G, NROW, 2048, 512);
  lstm_scan<<<dim3(224, 2), 256, 0, stream>>>(G, uvf, uvb, hstate, Xin, Vout, bar);

  // horizontal stage
  gemm_bt<bf16_t, true><<<dim3(16, 392), 256, 0, stream>>>(
      Vout, whf, whb, h_b_f, h_b_b, G, NROW, 2048, 512);
  lstm_scan<<<dim3(224, 2), 256, 0, stream>>>(G, uhf, uhb, hstate, Vout, Hout, bar + 3584);

  // fused 1x1 conv + softmax + scatter, then final attention GEMM
  conv_softmax<<<dim3(392), 256, 0, stream>>>(Hout, cwp, cbp, Wscr, NROW, 512);
  final_gemm<<<dim3(7, 4, 64), 256, 0, stream>>>(Wscr, xs, (float*)d_out);
}